// Round 8
// baseline (317.948 us; speedup 1.0000x reference)
//
#include <hip/hip_runtime.h>
#include <hip/hip_bf16.h>

#define B_ 1024
#define L_ 256
#define D_ 256
#define H_ 512
#define U_ 512
#define M_ (B_ * L_)   // 262144 rows of the big GEMM

#define BM 128
#define BN 64
#define BK 32
#define NKT 8          // D_/BK

typedef float f32x4 __attribute__((ext_vector_type(4)));
typedef short bf16x8 __attribute__((ext_vector_type(8)));  // 8 bf16 in 4 VGPRs

__device__ __forceinline__ short f2bf(float f) {
  // round-to-nearest-even fp32 -> bf16 (inputs are finite, no NaN handling)
  unsigned u = __float_as_uint(f);
  u += 0x7fffu + ((u >> 16) & 1u);
  return (short)(u >> 16);
}

__device__ __forceinline__ void load16_g2l(const void* g, void* l) {
  // async global->LDS, 16B per lane; LDS dest must be uniform-base + lane*16
  __builtin_amdgcn_global_load_lds(
      (const __attribute__((address_space(1))) unsigned int*)g,
      (__attribute__((address_space(3))) unsigned int*)l, 16, 0, 0);
}

__device__ __forceinline__ float fast_tanh(float x) {
  float e = __expf(2.0f * x);               // v_exp_f32 based, ~1ulp
  return 1.0f - 2.0f * __builtin_amdgcn_rcpf(e + 1.0f);
}

// ---------------- prep: W1 [D,U] fp32 -> W1T [U,D] bf16 ----------------
__global__ void k_w1t(const float* __restrict__ W1, short* __restrict__ W1T) {
  int idx = blockIdx.x * 256 + threadIdx.x;   // over U_*D_ = 131072
  int u = idx >> 8;      // / D_
  int d = idx & 255;
  W1T[idx] = f2bf(W1[(size_t)d * U_ + u]);
}

// ---------------- projh[b,u] = hidden[b,:] @ W2[:,u] + b1[u] + b2[u] ----------------
__global__ void k_projh(const float* __restrict__ hidden, const float* __restrict__ W2,
                        const float* __restrict__ b1, const float* __restrict__ b2,
                        float* __restrict__ ph) {
  int u = blockIdx.x * 256 + threadIdx.x;
  int b0 = blockIdx.y * 8;
  float acc[8] = {0.f, 0.f, 0.f, 0.f, 0.f, 0.f, 0.f, 0.f};
  for (int h = 0; h < H_; ++h) {
    float w = W2[(size_t)h * U_ + u];
#pragma unroll
    for (int i = 0; i < 8; ++i) acc[i] = fmaf(hidden[(size_t)(b0 + i) * H_ + h], w, acc[i]);
  }
  float bias = b1[u] + b2[u];
#pragma unroll
  for (int i = 0; i < 8; ++i) ph[(size_t)(b0 + i) * U_ + u] = acc[i] + bias;
}

// ---------------- main: logits partials via bf16 MFMA + tanh + Wv reduce ----------------
// 128x64x32 tile: acc 32 VGPR/thread -> 4-5 waves/SIMD; LDS 24 KB (A,B both dbuf)
// -> ONE barrier per kt. grid 16384, XCD-chunked swizzle. 4 waves (2 wr x 2 wc).
// LDS slot rotation: slot = row*4 + ((chunk + (row>>2)) & 3)  [2-way reads = free;
// linear writes; B source pre-rotated so g2l's linear dest yields rotated layout].
__global__ __launch_bounds__(256, 4) void k_gemm(
    const float* __restrict__ F,    // [M_, D_] fp32 features
    const short* __restrict__ W1T,  // [U_, D_] bf16
    const float* __restrict__ ph,   // [B_, U_]
    const float* __restrict__ Wv,   // [U_]
    float* __restrict__ logits) {   // [M_], pre-zeroed
  __shared__ __align__(16) short As[2][BM * BK];   // 2 x 8 KB
  __shared__ __align__(16) short Bs[2][BN * BK];   // 2 x 4 KB

  const int tid = threadIdx.x;
  const int lane = tid & 63;
  const int hi = lane >> 4;          // k-chunk 0..3 (8 bf16 each) within BK=32
  const int wid = tid >> 6;
  const int wr = wid >> 1, wc = wid & 1;
  // XCD swizzle: 16384 % 8 == 0 -> bijective; blocks sharing an A-tile stay on one XCD
  const int tile = ((blockIdx.x & 7) << 11) | (blockIdx.x >> 3);
  const int ntile = tile & 7;
  const int mtile = tile >> 3;
  const int m0 = mtile * BM;
  const int n0 = ntile * BN;
  const int b = m0 >> 8;             // 128-row tile lies within one batch

  // ---- A staging: 512 slots (128 rows x 4), 2 per thread, linear writes ----
  // slot s: row = s>>2, holds global chunk c = ((s&3) - (row>>2)) & 3
  const float* agp0;
  const float* agp1;
  {
    int s0 = tid, s1 = 256 + tid;
    int r0 = s0 >> 2, r1 = s1 >> 2;
    int c0 = ((s0 & 3) - (r0 >> 2)) & 3;
    int c1 = ((s1 & 3) - (r1 >> 2)) & 3;
    agp0 = F + (size_t)(m0 + r0) * D_ + c0 * 8;
    agp1 = F + (size_t)(m0 + r1) * D_ + c1 * 8;
  }
  // ---- B staging: 256 slots (64 n x 4), 1 per thread via g2l (linear dest) ----
  const short* bgp;
  {
    int n = tid >> 2;
    int c = ((tid & 3) - (n >> 2)) & 3;
    bgp = W1T + (size_t)(n0 + n) * D_ + c * 8;
  }

  f32x4 acc[4][2];
  const f32x4 fz = {0.f, 0.f, 0.f, 0.f};
#pragma unroll
  for (int mi = 0; mi < 4; ++mi) {
    acc[mi][0] = fz;
    acc[mi][1] = fz;
  }

  // precomputed frag-read slots (constant across kt)
  int aslotr[4], bslotr[2];
#pragma unroll
  for (int mi = 0; mi < 4; ++mi) {
    int rA = wr * 64 + mi * 16 + (lane & 15);
    aslotr[mi] = rA * 4 + ((hi + (rA >> 2)) & 3);
  }
#pragma unroll
  for (int ni = 0; ni < 2; ++ni) {
    int nB = wc * 32 + ni * 16 + (lane & 15);
    bslotr[ni] = nB * 4 + ((hi + (nB >> 2)) & 3);
  }

  // ---- prologue: issue kt=0 loads ----
  f32x4 a0a = *(const f32x4*)(agp0);
  f32x4 a0b = *(const f32x4*)(agp0 + 4);
  f32x4 a1a = *(const f32x4*)(agp1);
  f32x4 a1b = *(const f32x4*)(agp1 + 4);
  agp0 += BK; agp1 += BK;
  load16_g2l(bgp, &Bs[0][(size_t)tid * 8]);
  bgp += BK;

  for (int kt = 0; kt < NKT; ++kt) {
    // cast A(kt) (compiler waits the loads) and write linear slots
    {
      bf16x8 w0, w1;
#pragma unroll
      for (int j = 0; j < 4; ++j) {
        w0[j] = f2bf(a0a[j]); w0[4 + j] = f2bf(a0b[j]);
        w1[j] = f2bf(a1a[j]); w1[4 + j] = f2bf(a1b[j]);
      }
      ((bf16x8*)As[kt & 1])[tid] = w0;
      ((bf16x8*)As[kt & 1])[256 + tid] = w1;
    }
    __syncthreads();   // lgkm: A(kt) visible; vmcnt(0): B(kt) g2l (1 phase old) done

    if (kt < NKT - 1) {
      // prefetch kt+1 (lands during compute; consumed after next barrier)
      a0a = *(const f32x4*)(agp0);
      a0b = *(const f32x4*)(agp0 + 4);
      a1a = *(const f32x4*)(agp1);
      a1b = *(const f32x4*)(agp1 + 4);
      agp0 += BK; agp1 += BK;
      load16_g2l(bgp, &Bs[(kt + 1) & 1][(size_t)tid * 8]);
      bgp += BK;
    }

    // fragments + 8 MFMA
    bf16x8 af[4], bfr[2];
    const bf16x8* As8 = (const bf16x8*)As[kt & 1];
    const bf16x8* Bs8 = (const bf16x8*)Bs[kt & 1];
#pragma unroll
    for (int mi = 0; mi < 4; ++mi) af[mi] = As8[aslotr[mi]];
    bfr[0] = Bs8[bslotr[0]];
    bfr[1] = Bs8[bslotr[1]];
#pragma unroll
    for (int mi = 0; mi < 4; ++mi) {
      acc[mi][0] = __builtin_amdgcn_mfma_f32_16x16x32_bf16(af[mi], bfr[0], acc[mi][0], 0, 0, 0);
      acc[mi][1] = __builtin_amdgcn_mfma_f32_16x16x32_bf16(af[mi], bfr[1], acc[mi][1], 0, 0, 0);
    }
  }

  // epilogue: x = acc + ph[b,u]; t = tanh(x); partial logit = sum_u t*Wv[u]
  const float* phr = ph + (size_t)b * U_;
  float phv[2], wvv[2];
#pragma unroll
  for (int ni = 0; ni < 2; ++ni) {
    int u = n0 + wc * 32 + ni * 16 + (lane & 15);
    phv[ni] = phr[u];
    wvv[ni] = Wv[u];
  }
#pragma unroll
  for (int mi = 0; mi < 4; ++mi) {
    float cs[4] = {0.f, 0.f, 0.f, 0.f};
#pragma unroll
    for (int ni = 0; ni < 2; ++ni) {
#pragma unroll
      for (int r = 0; r < 4; ++r) {
        float x = acc[mi][ni][r] + phv[ni];
        cs[r] += fast_tanh(x) * wvv[ni];
      }
    }
    // reduce across the 16 column-lanes (C layout: col = lane&15, row = hi*4+r)
#pragma unroll
    for (int off = 1; off < 16; off <<= 1) {
#pragma unroll
      for (int r = 0; r < 4; ++r) cs[r] += __shfl_xor(cs[r], off);
    }
    if ((lane & 15) == 0) {
      int g = m0 + wr * 64 + mi * 16 + hi * 4;
#pragma unroll
      for (int r = 0; r < 4; ++r) atomicAdd(&logits[g + r], cs[r]);
    }
  }
}

// ---------------- fused: softmax over L, then context[b,d] = sum_l w*F ----------------
__global__ void k_smctx(const float* __restrict__ logits, const float* __restrict__ F,
                        float* __restrict__ outw, float* __restrict__ ctx) {
  __shared__ float wl[L_];
  __shared__ f32x4 part[256];
  __shared__ float red[8];
  int b = blockIdx.x, t = threadIdx.x;
  float x = logits[(size_t)b * L_ + t];
  float m = x;
#pragma unroll
  for (int off = 32; off >= 1; off >>= 1) m = fmaxf(m, __shfl_xor(m, off));
  if ((t & 63) == 0) red[t >> 6] = m;
  __syncthreads();
  m = fmaxf(fmaxf(red[0], red[1]), fmaxf(red[2], red[3]));
  float e = __expf(x - m);
  float s = e;
#pragma unroll
  for (int off = 32; off >= 1; off >>= 1) s += __shfl_xor(s, off);
  if ((t & 63) == 0) red[4 + (t >> 6)] = s;
  __syncthreads();
  s = (red[4] + red[5]) + (red[6] + red[7]);
  float w = e / s;
  outw[(size_t)b * L_ + t] = w;
  wl[t] = w;
  __syncthreads();

  int lq = t >> 6, dq = t & 63;
  const f32x4* F4 = (const f32x4*)(F + (size_t)b * L_ * D_);
  f32x4 acc = {0.f, 0.f, 0.f, 0.f};
  for (int l = lq; l < L_; l += 4) acc += wl[l] * F4[l * 64 + dq];
  part[t] = acc;
  __syncthreads();
  if (lq == 0) {
    f32x4 r = (part[t] + part[t + 64]) + (part[t + 128] + part[t + 192]);
    ((f32x4*)ctx)[(size_t)b * 64 + dq] = r;
  }
}

extern "C" void kernel_launch(void* const* d_in, const int* in_sizes, int n_in,
                              void* d_out, int out_size, void* d_ws, size_t ws_size,
                              hipStream_t stream) {
  const float* F      = (const float*)d_in[0];  // [B,L,D]
  const float* hidden = (const float*)d_in[1];  // [B,H]
  const float* W1     = (const float*)d_in[2];  // [D,U]
  const float* b1     = (const float*)d_in[3];  // [U]
  const float* W2     = (const float*)d_in[4];  // [H,U]
  const float* b2     = (const float*)d_in[5];  // [U]
  const float* Wv     = (const float*)d_in[6];  // [U,1]
  // d_in[7] = bv: shift-invariant under softmax, unused

  float* out_ctx = (float*)d_out;                        // [B,D] = 262144 floats
  float* out_w   = out_ctx + (size_t)B_ * D_;            // [B,L,1] = 262144 floats

  char* ws = (char*)d_ws;
  short* W1T   = (short*)ws;                             // 256 KB bf16 [U,D]
  float* ph    = (float*)(ws + 262144);                  // 2 MB fp32 [B,U]
  float* logits = (float*)(ws + 262144 + 2097152);       // 1 MB fp32 [B*L]

  hipMemsetAsync(logits, 0, (size_t)M_ * sizeof(float), stream);
  k_w1t<<<512, 256, 0, stream>>>(W1, W1T);
  k_projh<<<dim3(2, 128), 256, 0, stream>>>(hidden, W2, b1, b2, ph);
  k_gemm<<<16384, 256, 0, stream>>>(F, W1T, ph, Wv, logits);
  k_smctx<<<1024, 256, 0, stream>>>(logits, F, out_w, out_ctx);
}

// Round 10
// 254.850 us; speedup vs baseline: 1.2476x; 1.2476x over previous
//
#include <hip/hip_runtime.h>
#include <hip/hip_bf16.h>

#define B_ 1024
#define L_ 256
#define D_ 256
#define H_ 512
#define U_ 512
#define M_ (B_ * L_)

#define BM 128   // rows per block; block covers ALL of U, full K in LDS

typedef float f32x4 __attribute__((ext_vector_type(4)));
typedef short bf16x8 __attribute__((ext_vector_type(8)));
typedef short bf16x4 __attribute__((ext_vector_type(4)));

__device__ __forceinline__ short f2bf(float f) {
  unsigned u = __float_as_uint(f);
  u += 0x7fffu + ((u >> 16) & 1u);
  return (short)(u >> 16);
}

__device__ __forceinline__ float fast_tanh(float x) {
  float e = __expf(2.0f * x);
  return 1.0f - 2.0f * __builtin_amdgcn_rcpf(e + 1.0f);
}

// ---------------- prep: W1 [D,U] fp32 -> W1F fragment-major bf16 ----------------
// chunk c = nb*8 + kb (nb = u/16, kb = d/32); within chunk, element order is
// exactly lane-major for a b-fragment: lane l holds u = nb*16 + (l&15),
// d = kb*32 + (l>>4)*8 + j  ->  flat offset c*512 + l*8 + j.
__global__ void k_w1f(const float* __restrict__ W1, short* __restrict__ W1F) {
  int i = blockIdx.x * 256 + threadIdx.x;   // over 131072
  int jj = i & 7;
  int no = (i >> 3) & 15;
  int kc = (i >> 7) & 3;
  int kb = (i >> 9) & 7;
  int nb = i >> 12;
  int u = nb * 16 + no;
  int d = kb * 32 + kc * 8 + jj;
  W1F[i] = f2bf(W1[(size_t)d * U_ + u]);
}

// ---------------- projh[b,u] = hidden[b,:] @ W2[:,u] + b1[u] + b2[u] ----------------
__global__ void k_projh(const float* __restrict__ hidden, const float* __restrict__ W2,
                        const float* __restrict__ b1, const float* __restrict__ b2,
                        float* __restrict__ ph) {
  int u = blockIdx.x * 256 + threadIdx.x;
  int b0 = blockIdx.y * 8;
  float acc[8] = {0.f, 0.f, 0.f, 0.f, 0.f, 0.f, 0.f, 0.f};
  for (int h = 0; h < H_; ++h) {
    float w = W2[(size_t)h * U_ + u];
#pragma unroll
    for (int i = 0; i < 8; ++i) acc[i] = fmaf(hidden[(size_t)(b0 + i) * H_ + h], w, acc[i]);
  }
  float bias = b1[u] + b2[u];
#pragma unroll
  for (int i = 0; i < 8; ++i) ph[(size_t)(b0 + i) * U_ + u] = acc[i] + bias;
}

// ---------------- main: 128 rows x full U, logits written directly ----------------
// A staged ONCE (full K, bf16, XOR-swizzled). B fragments read direct from
// L2-resident W1F (coalesced 1KB/instr), prefetched 1 kt ahead.
// wc splits the u-SUM across waves -> final cross-wave combine via csum LDS
// (R9 bug: direct store dropped the wc-half combine that atomicAdd used to do).
__global__ __launch_bounds__(256, 2) void k_gemm(
    const float* __restrict__ F,    // [M_, D_] fp32
    const short* __restrict__ W1F,  // fragment-major bf16
    const float* __restrict__ ph,   // [B_, U_]
    const float* __restrict__ Wv,   // [U_]
    float* __restrict__ logits) {   // [M_]
  __shared__ __align__(16) short As[BM * D_];   // 64 KB
  __shared__ float csum[2][BM];                 // 1 KB: per-wc-half row sums

  const int tid = threadIdx.x;
  const int lane = tid & 63;
  const int hi = lane >> 4;
  const int wid = tid >> 6;
  const int wr = wid >> 1, wc = wid & 1;
  const int m0 = blockIdx.x * BM;
  const int b = m0 >> 8;

  // ---- stage A: full 128x256 fp32 -> bf16 LDS, once ----
  // instr j: thread t reads row j*4 + (t>>6), k-quad (t&63) (f32x4, 1KB/wave contiguous)
  {
    const float* sp = F + (size_t)(m0 + (tid >> 6)) * D_ + (tid & 63) * 4;
    const int kq8 = (tid & 63) * 8;   // byte offset of the 4-bf16 quad within a row
#pragma unroll
    for (int jb = 0; jb < 2; ++jb) {
      f32x4 sv[16];
#pragma unroll
      for (int j = 0; j < 16; ++j)
        sv[j] = *(const f32x4*)(sp + (size_t)(jb * 16 + j) * 4 * D_);
#pragma unroll
      for (int j = 0; j < 16; ++j) {
        int row = (jb * 16 + j) * 4 + (tid >> 6);
        int boff = (row * 512 + kq8) ^ ((row & 7) << 4);
        bf16x4 w;
#pragma unroll
        for (int q = 0; q < 4; ++q) w[q] = f2bf(sv[j][q]);
        *(bf16x4*)((char*)As + boff) = w;
      }
    }
  }
  __syncthreads();

  f32x4 acc[4][4];
  float cs[4][4];
  const f32x4 fz = {0.f, 0.f, 0.f, 0.f};
#pragma unroll
  for (int mi = 0; mi < 4; ++mi)
#pragma unroll
    for (int x = 0; x < 4; ++x) { acc[mi][x] = fz; cs[mi][x] = 0.f; }

  // B fragment base: chunk(nt,kt,ni) = nt*64 + wc*32 + ni*8 + kt, addr = chunk*512 + lane*8
  const short* bbase = W1F + (size_t)(wc * 32) * 512 + lane * 8;
  bf16x8 bcur[4], bnxt[4];
#pragma unroll
  for (int ni = 0; ni < 4; ++ni)
    bcur[ni] = *(const bf16x8*)(bbase + (size_t)(ni * 8) * 512);

  const float* phr = ph + (size_t)b * U_;
  const int rbase = wr * 64 + (lane & 15);

  for (int nt = 0; nt < 4; ++nt) {
#pragma unroll
    for (int kt = 0; kt < 8; ++kt) {
      // prefetch (nt,kt+1) — carries into next nt at kt==7
      if (nt * 8 + kt < 31) {
        const int ktn = (kt + 1) & 7;
        const int ntn64 = (nt + ((kt + 1) >> 3)) * 64;
#pragma unroll
        for (int ni = 0; ni < 4; ++ni)
          bnxt[ni] = *(const bf16x8*)(bbase + (size_t)(ntn64 + ni * 8 + ktn) * 512);
      }
      // A fragments from LDS (swizzled; ~2-way conflicts = free)
      bf16x8 af[4];
#pragma unroll
      for (int mi = 0; mi < 4; ++mi) {
        int rA = rbase + mi * 16;
        int boff = (rA * 512 + kt * 64 + hi * 16) ^ ((rA & 7) << 4);
        af[mi] = *(const bf16x8*)((const char*)As + boff);
      }
#pragma unroll
      for (int mi = 0; mi < 4; ++mi) {
        acc[mi][0] = __builtin_amdgcn_mfma_f32_16x16x32_bf16(af[mi], bcur[0], acc[mi][0], 0, 0, 0);
        acc[mi][1] = __builtin_amdgcn_mfma_f32_16x16x32_bf16(af[mi], bcur[1], acc[mi][1], 0, 0, 0);
        acc[mi][2] = __builtin_amdgcn_mfma_f32_16x16x32_bf16(af[mi], bcur[2], acc[mi][2], 0, 0, 0);
        acc[mi][3] = __builtin_amdgcn_mfma_f32_16x16x32_bf16(af[mi], bcur[3], acc[mi][3], 0, 0, 0);
      }
#pragma unroll
      for (int ni = 0; ni < 4; ++ni) bcur[ni] = bnxt[ni];
    }
    // epilogue for this ntile: cs += tanh(acc + ph) * Wv ; reset acc
#pragma unroll
    for (int ni = 0; ni < 4; ++ni) {
      int u = nt * 128 + wc * 64 + ni * 16 + (lane & 15);
      float phv = phr[u];
      float wvv = Wv[u];
#pragma unroll
      for (int mi = 0; mi < 4; ++mi) {
#pragma unroll
        for (int r = 0; r < 4; ++r) {
          float x = acc[mi][ni][r] + phv;
          cs[mi][r] += fast_tanh(x) * wvv;
        }
      }
    }
#pragma unroll
    for (int mi = 0; mi < 4; ++mi)
#pragma unroll
      for (int x = 0; x < 4; ++x) acc[mi][x] = fz;
  }

  // reduce cs across the 16 column-lanes, deposit per-wc half, combine, store
#pragma unroll
  for (int mi = 0; mi < 4; ++mi) {
#pragma unroll
    for (int off = 1; off < 16; off <<= 1) {
#pragma unroll
      for (int r = 0; r < 4; ++r) cs[mi][r] += __shfl_xor(cs[mi][r], off);
    }
    if ((lane & 15) == 0) {
      int rloc = wr * 64 + mi * 16 + hi * 4;   // row within the block (C: row = hi*4+r)
#pragma unroll
      for (int r = 0; r < 4; ++r) csum[wc][rloc + r] = cs[mi][r];
    }
  }
  __syncthreads();
  if (tid < BM) logits[m0 + tid] = csum[0][tid] + csum[1][tid];
}

// ---------------- fused: softmax over L, then context[b,d] = sum_l w*F ----------------
__global__ void k_smctx(const float* __restrict__ logits, const float* __restrict__ F,
                        float* __restrict__ outw, float* __restrict__ ctx) {
  __shared__ float wl[L_];
  __shared__ f32x4 part[256];
  __shared__ float red[8];
  int b = blockIdx.x, t = threadIdx.x;
  float x = logits[(size_t)b * L_ + t];
  float m = x;
#pragma unroll
  for (int off = 32; off >= 1; off >>= 1) m = fmaxf(m, __shfl_xor(m, off));
  if ((t & 63) == 0) red[t >> 6] = m;
  __syncthreads();
  m = fmaxf(fmaxf(red[0], red[1]), fmaxf(red[2], red[3]));
  float e = __expf(x - m);
  float s = e;
#pragma unroll
  for (int off = 32; off >= 1; off >>= 1) s += __shfl_xor(s, off);
  if ((t & 63) == 0) red[4 + (t >> 6)] = s;
  __syncthreads();
  s = (red[4] + red[5]) + (red[6] + red[7]);
  float w = e / s;
  outw[(size_t)b * L_ + t] = w;
  wl[t] = w;
  __syncthreads();

  int lq = t >> 6, dq = t & 63;
  const f32x4* F4 = (const f32x4*)(F + (size_t)b * L_ * D_);
  f32x4 acc = {0.f, 0.f, 0.f, 0.f};
  for (int l = lq; l < L_; l += 4) acc += wl[l] * F4[l * 64 + dq];
  part[t] = acc;
  __syncthreads();
  if (lq == 0) {
    f32x4 r = (part[t] + part[t + 64]) + (part[t + 128] + part[t + 192]);
    ((f32x4*)ctx)[(size_t)b * 64 + dq] = r;
  }
}

extern "C" void kernel_launch(void* const* d_in, const int* in_sizes, int n_in,
                              void* d_out, int out_size, void* d_ws, size_t ws_size,
                              hipStream_t stream) {
  const float* F      = (const float*)d_in[0];
  const float* hidden = (const float*)d_in[1];
  const float* W1     = (const float*)d_in[2];
  const float* b1     = (const float*)d_in[3];
  const float* W2     = (const float*)d_in[4];
  const float* b2     = (const float*)d_in[5];
  const float* Wv     = (const float*)d_in[6];
  // d_in[7] = bv: shift-invariant under softmax, unused

  float* out_ctx = (float*)d_out;                 // [B,D]
  float* out_w   = out_ctx + (size_t)B_ * D_;     // [B,L]

  char* ws = (char*)d_ws;
  short* W1F    = (short*)ws;                     // 256 KB fragment-major bf16
  float* ph     = (float*)(ws + 262144);          // 2 MB fp32 [B,U]
  float* logits = (float*)(ws + 262144 + 2097152);// 1 MB fp32 [M_] (fully overwritten)

  k_w1f<<<512, 256, 0, stream>>>(W1, W1F);
  k_projh<<<dim3(2, 128), 256, 0, stream>>>(hidden, W2, b1, b2, ph);
  k_gemm<<<2048, 256, 0, stream>>>(F, W1F, ph, Wv, logits);
  k_smctx<<<1024, 256, 0, stream>>>(logits, F, out_w, out_ctx);
}